// Round 13
// baseline (415.451 us; speedup 1.0000x reference)
//
#include <hip/hip_runtime.h>
#include <hip/hip_bf16.h>
#include <cstdint>
#include <cstddef>

#define HIDDEN 2048
#define NHEADS 16
#define NKV    8
#define HD     128
#define QS     (NHEADS*HD)      // 2048
#define KVS    (NKV*HD)         // 1024
#define OC     (QS + 2*KVS)     // 4096
#define BB     2
#define SS     2048
#define ROWS   (BB*SS)          // 4096

typedef __bf16 bf16;
typedef __bf16 bf16x8 __attribute__((ext_vector_type(8)));
typedef float  f32x4  __attribute__((ext_vector_type(4)));
typedef float  f32x2  __attribute__((ext_vector_type(2)));
typedef int    i32x4  __attribute__((ext_vector_type(4)));

// ---------------- f32 -> bf16 convert (vectorized) ----------------
__global__ __launch_bounds__(256) void k_cvt(const float* __restrict__ src,
                                             bf16* __restrict__ dst, int n8) {
  int i = blockIdx.x * blockDim.x + threadIdx.x;
  int stride = gridDim.x * blockDim.x;
  for (; i < n8; i += stride) {
    const f32x4* s = (const f32x4*)(src + (size_t)i * 8);
    f32x4 a = s[0], b = s[1];
    bf16x8 o;
    o[0]=(bf16)a[0]; o[1]=(bf16)a[1]; o[2]=(bf16)a[2]; o[3]=(bf16)a[3];
    o[4]=(bf16)b[0]; o[5]=(bf16)b[1]; o[6]=(bf16)b[2]; o[7]=(bf16)b[3];
    *(bf16x8*)(dst + (size_t)i * 8) = o;
  }
}

// ---------------- RoPE cos/sin table: tbl[pos][i] = {cos, sin} ----------------
__global__ __launch_bounds__(256) void k_table(float* __restrict__ tbl) {
  int t = blockIdx.x * blockDim.x + threadIdx.x;   // t < SS*64
  int pos = t >> 6, i = t & 63;
  float freq = powf(10000.0f, -(float)i / 64.0f);
  float ang = (float)pos * freq;
  float sv, cv;
  sincosf(ang, &sv, &cv);
  f32x2 v; v[0] = cv; v[1] = sv;
  ((f32x2*)tbl)[t] = v;
}

// ---------------- async global->LDS helper ----------------
__device__ __forceinline__ void gll16(const void* g, void* l) {
  __builtin_amdgcn_global_load_lds((const __attribute__((address_space(1))) void*)g,
                                   (__attribute__((address_space(3))) void*)l, 16, 0, 0);
}

// ---------------- GEMM: C[M][N] = A[M][K] * Bw[N][K]^T  (bf16 in, f32 accum, OT out) ----------------
template <typename OT>
__global__ __launch_bounds__(256) void k_gemm(const bf16* __restrict__ A,
                                              const bf16* __restrict__ Bw,
                                              OT* __restrict__ C,
                                              int M, int N, int K) {
  const int tid = threadIdx.x;
  const int lane = tid & 63;
  const int w = tid >> 6;
  const int m0 = blockIdx.y * 128, n0 = blockIdx.x * 128;
  __shared__ bf16 As[128 * 32];
  __shared__ bf16 Bs[128 * 32];
  f32x4 acc[4][4] = {};
  const int wm = (w >> 1) * 64, wn = (w & 1) * 64;
  const int lr = lane & 15, lg = lane >> 4;
  const int KT = K >> 5;
  for (int kt = 0; kt < KT; ++kt) {
    __syncthreads();
    for (int i = 0; i < 2; ++i) {
      int c = tid + i * 256;
      int row = c >> 2, kc = c & 3;
      gll16(A + (size_t)(m0 + row) * K + kt * 32 + kc * 8, As + (size_t)(c & ~63) * 8);
      gll16(Bw + (size_t)(n0 + row) * K + kt * 32 + kc * 8, Bs + (size_t)(c & ~63) * 8);
    }
    asm volatile("s_waitcnt vmcnt(0)" ::: "memory");
    __syncthreads();
    bf16x8 af[4], bfv[4];
    for (int i = 0; i < 4; ++i)
      af[i] = *(const bf16x8*)(As + (wm + i * 16 + lr) * 32 + lg * 8);
    for (int j = 0; j < 4; ++j)
      bfv[j] = *(const bf16x8*)(Bs + (wn + j * 16 + lr) * 32 + lg * 8);
    for (int i = 0; i < 4; ++i)
      for (int j = 0; j < 4; ++j)
        acc[i][j] = __builtin_amdgcn_mfma_f32_16x16x32_bf16(af[i], bfv[j], acc[i][j], 0, 0, 0);
  }
  for (int i = 0; i < 4; ++i)
    for (int j = 0; j < 4; ++j) {
      int col = n0 + wn + j * 16 + lr;
      for (int r = 0; r < 4; ++r) {
        int row = m0 + wm + i * 16 + lg * 4 + r;
        C[(size_t)row * N + col] = (OT)acc[i][j][r];
      }
    }
}

// ---------------- per-head RMSNorm + RoPE; one wave per (b,s,head24) ----------------
__global__ __launch_bounds__(256) void k_ropenorm(const bf16* __restrict__ qkv,
                                                  bf16* __restrict__ qb, bf16* __restrict__ kb,
                                                  const float* __restrict__ tbl,
                                                  const int* __restrict__ pos,
                                                  const float* __restrict__ qw,
                                                  const float* __restrict__ kw) {
  int gw = blockIdx.x * 4 + (threadIdx.x >> 6);
  int lane = threadIdx.x & 63;
  int h = gw % 24;
  int rem = gw / 24;
  int s = rem & (SS - 1);
  int b = rem >> 11;
  size_t row = (size_t)b * SS + s;
  int col0 = (h < 16) ? h * HD : QS + (h - 16) * HD;
  unsigned u = *(const unsigned*)(qkv + row * OC + col0 + lane * 2);
  float x0 = __uint_as_float((u & 0xffffu) << 16);
  float x1 = __uint_as_float(u & 0xffff0000u);
  float ssq = x0 * x0 + x1 * x1;
  for (int m = 1; m < 64; m <<= 1) ssq += __shfl_xor(ssq, m, 64);
  float r = rsqrtf(ssq * (1.0f / 128.0f) + 1e-6f);
  const float* wv = (h < 16) ? qw : kw;
  float y0 = x0 * r * wv[lane * 2], y1 = x1 * r * wv[lane * 2 + 1];
  float p0 = __shfl_xor(y0, 32, 64), p1 = __shfl_xor(y1, 32, 64);
  int p = pos[row];
  f32x4 cs = *(const f32x4*)(tbl + (size_t)p * 128 + (lane & 31) * 4); // c0,s0,c1,s1
  float o0, o1;
  if (lane < 32) { o0 = y0 * cs[0] - p0 * cs[1]; o1 = y1 * cs[2] - p1 * cs[3]; }
  else           { o0 = y0 * cs[0] + p0 * cs[1]; o1 = y1 * cs[2] + p1 * cs[3]; }
  bf16* dst; size_t drow;
  if (h < 16) { dst = qb; drow = ((size_t)b * NHEADS + h) * SS + s; }
  else        { dst = kb; drow = ((size_t)b * NKV + (h - 16)) * SS + s; }
  bf16 v0 = (bf16)o0, v1 = (bf16)o1;
  unsigned short q0, q1;
  __builtin_memcpy(&q0, &v0, 2); __builtin_memcpy(&q1, &v1, 2);
  *(unsigned*)(dst + drow * HD + lane * 2) = (unsigned)q0 | ((unsigned)q1 << 16);
}

// ---------------- V transpose: qkv v-cols -> vT[b][kv][d][s] ----------------
__global__ __launch_bounds__(256) void k_vt(const bf16* __restrict__ qkv,
                                            bf16* __restrict__ vT) {
  __shared__ bf16 T[64 * 136];       // 64 s-rows x (128 + 8 pad)
  int tid = threadIdx.x;
  int st = blockIdx.x, kv = blockIdx.y, b = blockIdx.z;
  int s0 = st * 64;
  for (int i = 0; i < 4; ++i) {      // 1024 chunks = 64 rows x 16 d-chunks
    int c = tid + i * 256;
    int sl = c >> 4, dc = c & 15;
    i32x4 v = *(const i32x4*)(qkv + (size_t)(b * SS + s0 + sl) * OC + QS + KVS + kv * HD + dc * 8);
    *(i32x4*)(T + sl * 136 + dc * 8) = v;
  }
  __syncthreads();
  for (int i = 0; i < 4; ++i) {
    int c = tid + i * 256;
    int d = c >> 3, sg = c & 7;
    bf16x8 o;
    for (int j = 0; j < 8; ++j) o[j] = T[(sg * 8 + j) * 136 + d];
    *(bf16x8*)(vT + ((size_t)(b * NKV + kv) * HD + d) * SS + s0 + sg * 8) = o;
  }
}

// ---------------- flash attention: 8 waves x 16 q-rows (QBLK=128), single-buffered LDS K/V ----------------
// Staging amortized over 2x compute vs R11. Same per-wave math (R9/R11-verified).
__global__ __launch_bounds__(512) void k_attn7(const bf16* __restrict__ qb,
                                               const bf16* __restrict__ kb,
                                               const bf16* __restrict__ vT,
                                               bf16* __restrict__ out) {
  __shared__ bf16 Kl[64 * 128];      // [kv][d], rows XOR-swizzled by (row&7)<<4
  __shared__ bf16 Vl[128 * 64];      // [d][kv], rows XOR-swizzled by (row&7)<<4
  const int tid = threadIdx.x, lane = tid & 63, w = tid >> 6;   // w in 0..7
  const int qtb = gridDim.x - 1 - blockIdx.x;   // heavy blocks dispatch first
  const int h = blockIdx.y, b = blockIdx.z;
  const int kvh = h >> 1;
  const int lr = lane & 15, lg = lane >> 4;
  const int qbase = qtb * 128 + w * 16;
  const float NEG = -3.0e38f;
  bf16x8 qf[4];
  {
    const bf16* qrow = qb + ((size_t)(b * NHEADS + h) * SS + qbase + lr) * HD;
    #pragma unroll
    for (int ks = 0; ks < 4; ++ks) qf[ks] = *(const bf16x8*)(qrow + ks * 32 + lg * 8);
  }
  f32x4 acc[8] = {};                 // acc[nt][r] = O[q=lg*4+r][d=nt*16+lr]
  float m_r = NEG, l_r = 0.0f;
  const bf16* Kg = kb + (size_t)(b * NKV + kvh) * SS * HD;
  const bf16* Vg = vT + (size_t)(b * NKV + kvh) * HD * SS;
  const int ntile = 2 * qtb + 2;     // tiles needed to cover qbase+127
  for (int t = 0; t < ntile; ++t) {
    const int kv0 = t * 64;
    __syncthreads();                 // protect previous tile's LDS from overwrite
    // ---- stage K tile: 1024 x 16B chunks over 512 threads ----
    #pragma unroll
    for (int i = 0; i < 2; ++i) {
      int c = tid + i * 512;
      int r_ = c >> 4, ch = c & 15;
      i32x4 v = *(const i32x4*)(Kg + (size_t)(kv0 + r_) * HD + ch * 8);
      *(i32x4*)((char*)Kl + ((r_ * 256 + ch * 16) ^ ((r_ & 7) << 4))) = v;
    }
    // ---- stage V^T tile: 1024 x 16B chunks ----
    #pragma unroll
    for (int i = 0; i < 2; ++i) {
      int c = tid + i * 512;
      int d = c >> 3, ch = c & 7;
      i32x4 v = *(const i32x4*)(Vg + (size_t)d * SS + kv0 + ch * 8);
      *(i32x4*)((char*)Vl + ((d * 128 + ch * 16) ^ ((d & 7) << 4))) = v;
    }
    __syncthreads();
    if (kv0 > qbase + 15) continue;  // this wave fully masked for this tile (barriers already passed)
    // ---- QK^T: S^T[kv][q] via MFMA; K A-fragments from LDS ----
    f32x4 sf[4];
    #pragma unroll
    for (int mt = 0; mt < 4; ++mt) {
      f32x4 a_ = {0.f, 0.f, 0.f, 0.f};
      const int rrow = mt * 16 + lr;
      #pragma unroll
      for (int ks = 0; ks < 4; ++ks) {
        bf16x8 kf = *(const bf16x8*)((char*)Kl + ((rrow * 256 + ks * 64 + lg * 16) ^ ((rrow & 7) << 4)));
        a_ = __builtin_amdgcn_mfma_f32_16x16x32_bf16(kf, qf[ks], a_, 0, 0, 0);
      }
      sf[mt] = a_;
    }
    // ---- scale + causal mask + online softmax (lane holds q=lr, kv=kv0+mt*16+lg*4+r) ----
    const float scl = 0.08838834764831845f;  // 1/sqrt(128)
    const int qg = qbase + lr;
    float pm = NEG;
    #pragma unroll
    for (int mt = 0; mt < 4; ++mt)
      #pragma unroll
      for (int r = 0; r < 4; ++r) {
        int kvg = kv0 + mt * 16 + lg * 4 + r;
        float v = sf[mt][r] * scl;
        if (kvg > qg) v = NEG;
        sf[mt][r] = v;
        pm = fmaxf(pm, v);
      }
    pm = fmaxf(pm, __shfl_xor(pm, 16, 64));
    pm = fmaxf(pm, __shfl_xor(pm, 32, 64));
    const float mn = fmaxf(m_r, pm);
    const float scale = __expf(m_r - mn);
    float ts = 0.f;
    #pragma unroll
    for (int mt = 0; mt < 4; ++mt)
      #pragma unroll
      for (int r = 0; r < 4; ++r) {
        float pv = __expf(sf[mt][r] - mn);     // masked -> 0
        sf[mt][r] = pv;
        ts += pv;
      }
    ts += __shfl_xor(ts, 16, 64);
    ts += __shfl_xor(ts, 32, 64);
    l_r = l_r * scale + ts;
    m_r = mn;
    // ---- rescale O: acc row q' = lg*4+r; lane lg*4+r has lr == q' ----
    float sr[4];
    #pragma unroll
    for (int r = 0; r < 4; ++r) sr[r] = __shfl(scale, lg * 4 + r, 64);
    #pragma unroll
    for (int nt = 0; nt < 8; ++nt)
      #pragma unroll
      for (int r = 0; r < 4; ++r) acc[nt][r] *= sr[r];
    // ---- PV: regroup P in-register to A-fragment layout (R9-verified) ----
    #pragma unroll
    for (int kk = 0; kk < 2; ++kk) {
      bf16x8 pa;
      #pragma unroll
      for (int j = 0; j < 8; ++j) {
        int srclane = ((lg & 1) * 2 + (j >> 2)) * 16 + lr;
        float v0 = __shfl(sf[2 * kk][j & 3], srclane, 64);
        float v1 = __shfl(sf[2 * kk + 1][j & 3], srclane, 64);
        pa[j] = (bf16)((lg & 2) ? v1 : v0);
      }
      #pragma unroll
      for (int nt = 0; nt < 8; ++nt) {
        const int d = nt * 16 + lr;
        bf16x8 vbf = *(const bf16x8*)((char*)Vl + ((d * 128 + kk * 64 + lg * 16) ^ ((d & 7) << 4)));
        acc[nt] = __builtin_amdgcn_mfma_f32_16x16x32_bf16(pa, vbf, acc[nt], 0, 0, 0);
      }
    }
  }
  // ---- epilogue: normalize rows and store ----
  const float inv = 1.0f / l_r;     // lane holds inv for q=lr
  float ir[4];
  #pragma unroll
  for (int r = 0; r < 4; ++r) ir[r] = __shfl(inv, lg * 4 + r, 64);
  #pragma unroll
  for (int nt = 0; nt < 8; ++nt)
    #pragma unroll
    for (int r = 0; r < 4; ++r) {
      size_t row = (size_t)b * SS + qbase + lg * 4 + r;
      out[row * QS + h * HD + nt * 16 + lr] = (bf16)(acc[nt][r] * ir[r]);
    }
}

// ---------------- launcher ----------------
extern "C" void kernel_launch(void* const* d_in, const int* in_sizes, int n_in,
                              void* d_out, int out_size, void* d_ws, size_t ws_size,
                              hipStream_t stream) {
  const int*   pos  = (const int*)d_in[0];
  const float* hid  = (const float*)d_in[1];
  const float* wqkv = (const float*)d_in[2];
  const float* wo   = (const float*)d_in[3];
  const float* qw   = (const float*)d_in[4];
  const float* kw   = (const float*)d_in[5];
  char* ws = (char*)d_ws;
  bf16* hid_bf  = (bf16*)(ws + 0);          // 16MB, reused as attn_out
  bf16* attn_o  = hid_bf;
  bf16* wqkv_bf = (bf16*)(ws + 16777216);   // 16MB, reused as q_buf
  bf16* q_buf   = wqkv_bf;
  bf16* k_buf   = (bf16*)(ws + 33554432);   // 8MB, reused as wo_bf
  bf16* wo_bf   = k_buf;
  bf16* qkv     = (bf16*)(ws + 41943040);   // 32MB
  bf16* vT      = (bf16*)(ws + 75497472);   // 8MB
  float* tbl    = (float*)(ws + 83886080);  // 1MB

  k_cvt<<<dim3(2048), dim3(256), 0, stream>>>(hid,  hid_bf,  ROWS * HIDDEN / 8);
  k_cvt<<<dim3(2048), dim3(256), 0, stream>>>(wqkv, wqkv_bf, OC * HIDDEN / 8);
  k_table<<<dim3(512), dim3(256), 0, stream>>>(tbl);
  k_gemm<bf16><<<dim3(OC / 128, ROWS / 128), dim3(256), 0, stream>>>(
      hid_bf, wqkv_bf, qkv, ROWS, OC, HIDDEN);
  k_ropenorm<<<dim3(ROWS * 24 / 4), dim3(256), 0, stream>>>(
      qkv, q_buf, k_buf, tbl, pos, qw, kw);
  k_vt<<<dim3(SS / 64, NKV, BB), dim3(256), 0, stream>>>(qkv, vT);
  k_attn7<<<dim3(SS / 128, NHEADS, BB), dim3(512), 0, stream>>>(
      q_buf, k_buf, vT, attn_o);
  k_cvt<<<dim3(2048), dim3(256), 0, stream>>>(wo, wo_bf, HIDDEN * QS / 8);
  k_gemm<float><<<dim3(HIDDEN / 128, ROWS / 128), dim3(256), 0, stream>>>(
      attn_o, wo_bf, (float*)d_out, ROWS, HIDDEN, QS);
}

// Round 14
// 374.421 us; speedup vs baseline: 1.1096x; 1.1096x over previous
//
#include <hip/hip_runtime.h>
#include <hip/hip_bf16.h>
#include <cstdint>
#include <cstddef>

#define HIDDEN 2048
#define NHEADS 16
#define NKV    8
#define HD     128
#define QS     (NHEADS*HD)      // 2048
#define KVS    (NKV*HD)         // 1024
#define OC     (QS + 2*KVS)     // 4096
#define BB     2
#define SS     2048
#define ROWS   (BB*SS)          // 4096

typedef __bf16 bf16;
typedef __bf16 bf16x8 __attribute__((ext_vector_type(8)));
typedef float  f32x4  __attribute__((ext_vector_type(4)));
typedef float  f32x2  __attribute__((ext_vector_type(2)));
typedef int    i32x4  __attribute__((ext_vector_type(4)));

// ---------------- f32 -> bf16 convert (vectorized) ----------------
__global__ __launch_bounds__(256) void k_cvt(const float* __restrict__ src,
                                             bf16* __restrict__ dst, int n8) {
  int i = blockIdx.x * blockDim.x + threadIdx.x;
  int stride = gridDim.x * blockDim.x;
  for (; i < n8; i += stride) {
    const f32x4* s = (const f32x4*)(src + (size_t)i * 8);
    f32x4 a = s[0], b = s[1];
    bf16x8 o;
    o[0]=(bf16)a[0]; o[1]=(bf16)a[1]; o[2]=(bf16)a[2]; o[3]=(bf16)a[3];
    o[4]=(bf16)b[0]; o[5]=(bf16)b[1]; o[6]=(bf16)b[2]; o[7]=(bf16)b[3];
    *(bf16x8*)(dst + (size_t)i * 8) = o;
  }
}

// ---------------- RoPE cos/sin table: tbl[pos][i] = {cos, sin} ----------------
__global__ __launch_bounds__(256) void k_table(float* __restrict__ tbl) {
  int t = blockIdx.x * blockDim.x + threadIdx.x;   // t < SS*64
  int pos = t >> 6, i = t & 63;
  float freq = powf(10000.0f, -(float)i / 64.0f);
  float ang = (float)pos * freq;
  float sv, cv;
  sincosf(ang, &sv, &cv);
  f32x2 v; v[0] = cv; v[1] = sv;
  ((f32x2*)tbl)[t] = v;
}

// ---------------- async global->LDS helper ----------------
__device__ __forceinline__ void gll16(const void* g, void* l) {
  __builtin_amdgcn_global_load_lds((const __attribute__((address_space(1))) void*)g,
                                   (__attribute__((address_space(3))) void*)l, 16, 0, 0);
}

// ---------------- GEMM: C[M][N] = A[M][K] * Bw[N][K]^T  (bf16 in, f32 accum, OT out) ----------------
template <typename OT>
__global__ __launch_bounds__(256) void k_gemm(const bf16* __restrict__ A,
                                              const bf16* __restrict__ Bw,
                                              OT* __restrict__ C,
                                              int M, int N, int K) {
  const int tid = threadIdx.x;
  const int lane = tid & 63;
  const int w = tid >> 6;
  const int m0 = blockIdx.y * 128, n0 = blockIdx.x * 128;
  __shared__ bf16 As[128 * 32];
  __shared__ bf16 Bs[128 * 32];
  f32x4 acc[4][4] = {};
  const int wm = (w >> 1) * 64, wn = (w & 1) * 64;
  const int lr = lane & 15, lg = lane >> 4;
  const int KT = K >> 5;
  for (int kt = 0; kt < KT; ++kt) {
    __syncthreads();
    for (int i = 0; i < 2; ++i) {
      int c = tid + i * 256;
      int row = c >> 2, kc = c & 3;
      gll16(A + (size_t)(m0 + row) * K + kt * 32 + kc * 8, As + (size_t)(c & ~63) * 8);
      gll16(Bw + (size_t)(n0 + row) * K + kt * 32 + kc * 8, Bs + (size_t)(c & ~63) * 8);
    }
    asm volatile("s_waitcnt vmcnt(0)" ::: "memory");
    __syncthreads();
    bf16x8 af[4], bfv[4];
    for (int i = 0; i < 4; ++i)
      af[i] = *(const bf16x8*)(As + (wm + i * 16 + lr) * 32 + lg * 8);
    for (int j = 0; j < 4; ++j)
      bfv[j] = *(const bf16x8*)(Bs + (wn + j * 16 + lr) * 32 + lg * 8);
    for (int i = 0; i < 4; ++i)
      for (int j = 0; j < 4; ++j)
        acc[i][j] = __builtin_amdgcn_mfma_f32_16x16x32_bf16(af[i], bfv[j], acc[i][j], 0, 0, 0);
  }
  for (int i = 0; i < 4; ++i)
    for (int j = 0; j < 4; ++j) {
      int col = n0 + wn + j * 16 + lr;
      for (int r = 0; r < 4; ++r) {
        int row = m0 + wm + i * 16 + lg * 4 + r;
        C[(size_t)row * N + col] = (OT)acc[i][j][r];
      }
    }
}

// ---------------- per-head RMSNorm + RoPE; one wave per (b,s,head24) ----------------
__global__ __launch_bounds__(256) void k_ropenorm(const bf16* __restrict__ qkv,
                                                  bf16* __restrict__ qb, bf16* __restrict__ kb,
                                                  const float* __restrict__ tbl,
                                                  const int* __restrict__ pos,
                                                  const float* __restrict__ qw,
                                                  const float* __restrict__ kw) {
  int gw = blockIdx.x * 4 + (threadIdx.x >> 6);
  int lane = threadIdx.x & 63;
  int h = gw % 24;
  int rem = gw / 24;
  int s = rem & (SS - 1);
  int b = rem >> 11;
  size_t row = (size_t)b * SS + s;
  int col0 = (h < 16) ? h * HD : QS + (h - 16) * HD;
  unsigned u = *(const unsigned*)(qkv + row * OC + col0 + lane * 2);
  float x0 = __uint_as_float((u & 0xffffu) << 16);
  float x1 = __uint_as_float(u & 0xffff0000u);
  float ssq = x0 * x0 + x1 * x1;
  for (int m = 1; m < 64; m <<= 1) ssq += __shfl_xor(ssq, m, 64);
  float r = rsqrtf(ssq * (1.0f / 128.0f) + 1e-6f);
  const float* wv = (h < 16) ? qw : kw;
  float y0 = x0 * r * wv[lane * 2], y1 = x1 * r * wv[lane * 2 + 1];
  float p0 = __shfl_xor(y0, 32, 64), p1 = __shfl_xor(y1, 32, 64);
  int p = pos[row];
  f32x4 cs = *(const f32x4*)(tbl + (size_t)p * 128 + (lane & 31) * 4); // c0,s0,c1,s1
  float o0, o1;
  if (lane < 32) { o0 = y0 * cs[0] - p0 * cs[1]; o1 = y1 * cs[2] - p1 * cs[3]; }
  else           { o0 = y0 * cs[0] + p0 * cs[1]; o1 = y1 * cs[2] + p1 * cs[3]; }
  bf16* dst; size_t drow;
  if (h < 16) { dst = qb; drow = ((size_t)b * NHEADS + h) * SS + s; }
  else        { dst = kb; drow = ((size_t)b * NKV + (h - 16)) * SS + s; }
  bf16 v0 = (bf16)o0, v1 = (bf16)o1;
  unsigned short q0, q1;
  __builtin_memcpy(&q0, &v0, 2); __builtin_memcpy(&q1, &v1, 2);
  *(unsigned*)(dst + drow * HD + lane * 2) = (unsigned)q0 | ((unsigned)q1 << 16);
}

// ---------------- V transpose: qkv v-cols -> vT[b][kv][d][s] ----------------
__global__ __launch_bounds__(256) void k_vt(const bf16* __restrict__ qkv,
                                            bf16* __restrict__ vT) {
  __shared__ bf16 T[64 * 136];       // 64 s-rows x (128 + 8 pad)
  int tid = threadIdx.x;
  int st = blockIdx.x, kv = blockIdx.y, b = blockIdx.z;
  int s0 = st * 64;
  for (int i = 0; i < 4; ++i) {      // 1024 chunks = 64 rows x 16 d-chunks
    int c = tid + i * 256;
    int sl = c >> 4, dc = c & 15;
    i32x4 v = *(const i32x4*)(qkv + (size_t)(b * SS + s0 + sl) * OC + QS + KVS + kv * HD + dc * 8);
    *(i32x4*)(T + sl * 136 + dc * 8) = v;
  }
  __syncthreads();
  for (int i = 0; i < 4; ++i) {
    int c = tid + i * 256;
    int d = c >> 3, sg = c & 7;
    bf16x8 o;
    for (int j = 0; j < 8; ++j) o[j] = T[(sg * 8 + j) * 136 + d];
    *(bf16x8*)(vT + ((size_t)(b * NKV + kv) * HD + d) * SS + s0 + sg * 8) = o;
  }
}

// ---------------- flash attention: R11 structure + global_load_lds staging ----------------
// 4 waves x 16 q-rows, QBLK=64, single-buffered LDS, 2 barriers/tile.
// Staging via global_load_lds (linear LDS dest) with INVERSE-SWIZZLED global source
// (rule #21c): read swizzle byte^=(row&7)<<4 is matched by permuting the source
// chunk column ch ^= (row&7). Reads identical to R11 (verified).
__global__ __launch_bounds__(256) void k_attn8(const bf16* __restrict__ qb,
                                               const bf16* __restrict__ kb,
                                               const bf16* __restrict__ vT,
                                               bf16* __restrict__ out) {
  __shared__ bf16 Kl[64 * 128];      // [kv][d], rows XOR-swizzled by (row&7)<<4
  __shared__ bf16 Vl[128 * 64];      // [d][kv], rows XOR-swizzled by (row&7)<<4
  const int tid = threadIdx.x, lane = tid & 63, w = tid >> 6;
  const int qt = gridDim.x - 1 - blockIdx.x;   // heavy tiles dispatch first
  const int h = blockIdx.y, b = blockIdx.z;
  const int kvh = h >> 1;
  const int lr = lane & 15, lg = lane >> 4;
  const int qbase = qt * 64 + w * 16;
  const float NEG = -3.0e38f;
  bf16x8 qf[4];
  {
    const bf16* qrow = qb + ((size_t)(b * NHEADS + h) * SS + qbase + lr) * HD;
    #pragma unroll
    for (int ks = 0; ks < 4; ++ks) qf[ks] = *(const bf16x8*)(qrow + ks * 32 + lg * 8);
  }
  f32x4 acc[8] = {};                 // acc[nt][r] = O[q=lg*4+r][d=nt*16+lr]
  float m_r = NEG, l_r = 0.0f;
  const bf16* Kg = kb + (size_t)(b * NKV + kvh) * SS * HD;
  const bf16* Vg = vT + (size_t)(b * NKV + kvh) * HD * SS;
  for (int t = 0; t <= qt; ++t) {
    const int kv0 = t * 64;
    __syncthreads();                 // protect previous tile's LDS from overwrite
    // ---- stage K tile via global_load_lds: linear LDS slot c gets global chunk
    //      (r = c>>4, ch = (c&15)^(r&7)) so that the swizzled READ finds chunk
    //      (r,ch) at byte (r*256+ch*16)^((r&7)<<4). Coalesced within each row. ----
    #pragma unroll
    for (int i = 0; i < 4; ++i) {
      int c = tid + i * 256;
      int r_ = c >> 4;
      int ch = (c & 15) ^ (r_ & 7);
      gll16(Kg + (size_t)(kv0 + r_) * HD + ch * 8, Kl + (size_t)(c & ~63) * 8);
    }
    // ---- stage V^T tile: linear slot c gets (d = c>>3, ch = (c&7)^(d&7)) ----
    #pragma unroll
    for (int i = 0; i < 4; ++i) {
      int c = tid + i * 256;
      int d = c >> 3;
      int ch = (c & 7) ^ (d & 7);
      gll16(Vg + (size_t)d * SS + kv0 + ch * 8, Vl + (size_t)(c & ~63) * 8);
    }
    asm volatile("s_waitcnt vmcnt(0)" ::: "memory");
    __syncthreads();
    // ---- QK^T: S^T[kv][q] via MFMA; K A-fragments from LDS (swizzled read) ----
    f32x4 sf[4];
    #pragma unroll
    for (int mt = 0; mt < 4; ++mt) {
      f32x4 a_ = {0.f, 0.f, 0.f, 0.f};
      const int rrow = mt * 16 + lr;
      #pragma unroll
      for (int ks = 0; ks < 4; ++ks) {
        bf16x8 kf = *(const bf16x8*)((char*)Kl + ((rrow * 256 + ks * 64 + lg * 16) ^ ((rrow & 7) << 4)));
        a_ = __builtin_amdgcn_mfma_f32_16x16x32_bf16(kf, qf[ks], a_, 0, 0, 0);
      }
      sf[mt] = a_;
    }
    // ---- scale + causal mask + online softmax (lane holds q=lr, kv=kv0+mt*16+lg*4+r) ----
    const float scl = 0.08838834764831845f;  // 1/sqrt(128)
    const int qg = qbase + lr;
    float pm = NEG;
    #pragma unroll
    for (int mt = 0; mt < 4; ++mt)
      #pragma unroll
      for (int r = 0; r < 4; ++r) {
        int kvg = kv0 + mt * 16 + lg * 4 + r;
        float v = sf[mt][r] * scl;
        if (kvg > qg) v = NEG;
        sf[mt][r] = v;
        pm = fmaxf(pm, v);
      }
    pm = fmaxf(pm, __shfl_xor(pm, 16, 64));
    pm = fmaxf(pm, __shfl_xor(pm, 32, 64));
    const float mn = fmaxf(m_r, pm);
    const float scale = __expf(m_r - mn);
    float ts = 0.f;
    #pragma unroll
    for (int mt = 0; mt < 4; ++mt)
      #pragma unroll
      for (int r = 0; r < 4; ++r) {
        float pv = __expf(sf[mt][r] - mn);     // masked -> 0
        sf[mt][r] = pv;
        ts += pv;
      }
    ts += __shfl_xor(ts, 16, 64);
    ts += __shfl_xor(ts, 32, 64);
    l_r = l_r * scale + ts;
    m_r = mn;
    // ---- rescale O: acc row q' = lg*4+r; lane lg*4+r has lr == q' ----
    float sr[4];
    #pragma unroll
    for (int r = 0; r < 4; ++r) sr[r] = __shfl(scale, lg * 4 + r, 64);
    #pragma unroll
    for (int nt = 0; nt < 8; ++nt)
      #pragma unroll
      for (int r = 0; r < 4; ++r) acc[nt][r] *= sr[r];
    // ---- PV: regroup P in-register to A-fragment layout (R9-verified) ----
    #pragma unroll
    for (int kk = 0; kk < 2; ++kk) {
      bf16x8 pa;
      #pragma unroll
      for (int j = 0; j < 8; ++j) {
        int srclane = ((lg & 1) * 2 + (j >> 2)) * 16 + lr;
        float v0 = __shfl(sf[2 * kk][j & 3], srclane, 64);
        float v1 = __shfl(sf[2 * kk + 1][j & 3], srclane, 64);
        pa[j] = (bf16)((lg & 2) ? v1 : v0);
      }
      #pragma unroll
      for (int nt = 0; nt < 8; ++nt) {
        const int d = nt * 16 + lr;
        bf16x8 vbf = *(const bf16x8*)((char*)Vl + ((d * 128 + kk * 64 + lg * 16) ^ ((d & 7) << 4)));
        acc[nt] = __builtin_amdgcn_mfma_f32_16x16x32_bf16(pa, vbf, acc[nt], 0, 0, 0);
      }
    }
  }
  // ---- epilogue: normalize rows and store ----
  const float inv = 1.0f / l_r;     // lane holds inv for q=lr
  float ir[4];
  #pragma unroll
  for (int r = 0; r < 4; ++r) ir[r] = __shfl(inv, lg * 4 + r, 64);
  #pragma unroll
  for (int nt = 0; nt < 8; ++nt)
    #pragma unroll
    for (int r = 0; r < 4; ++r) {
      size_t row = (size_t)b * SS + qbase + lg * 4 + r;
      out[row * QS + h * HD + nt * 16 + lr] = (bf16)(acc[nt][r] * ir[r]);
    }
}

// ---------------- launcher ----------------
extern "C" void kernel_launch(void* const* d_in, const int* in_sizes, int n_in,
                              void* d_out, int out_size, void* d_ws, size_t ws_size,
                              hipStream_t stream) {
  const int*   pos  = (const int*)d_in[0];
  const float* hid  = (const float*)d_in[1];
  const float* wqkv = (const float*)d_in[2];
  const float* wo   = (const float*)d_in[3];
  const float* qw   = (const float*)d_in[4];
  const float* kw   = (const float*)d_in[5];
  char* ws = (char*)d_ws;
  bf16* hid_bf  = (bf16*)(ws + 0);          // 16MB, reused as attn_out
  bf16* attn_o  = hid_bf;
  bf16* wqkv_bf = (bf16*)(ws + 16777216);   // 16MB, reused as q_buf
  bf16* q_buf   = wqkv_bf;
  bf16* k_buf   = (bf16*)(ws + 33554432);   // 8MB, reused as wo_bf
  bf16* wo_bf   = k_buf;
  bf16* qkv     = (bf16*)(ws + 41943040);   // 32MB
  bf16* vT      = (bf16*)(ws + 75497472);   // 8MB
  float* tbl    = (float*)(ws + 83886080);  // 1MB

  k_cvt<<<dim3(2048), dim3(256), 0, stream>>>(hid,  hid_bf,  ROWS * HIDDEN / 8);
  k_cvt<<<dim3(2048), dim3(256), 0, stream>>>(wqkv, wqkv_bf, OC * HIDDEN / 8);
  k_table<<<dim3(512), dim3(256), 0, stream>>>(tbl);
  k_gemm<bf16><<<dim3(OC / 128, ROWS / 128), dim3(256), 0, stream>>>(
      hid_bf, wqkv_bf, qkv, ROWS, OC, HIDDEN);
  k_ropenorm<<<dim3(ROWS * 24 / 4), dim3(256), 0, stream>>>(
      qkv, q_buf, k_buf, tbl, pos, qw, kw);
  k_vt<<<dim3(SS / 64, NKV, BB), dim3(256), 0, stream>>>(qkv, vT);
  k_attn8<<<dim3(SS / 64, NHEADS, BB), dim3(256), 0, stream>>>(
      q_buf, k_buf, vT, attn_o);
  k_cvt<<<dim3(2048), dim3(256), 0, stream>>>(wo, wo_bf, HIDDEN * QS / 8);
  k_gemm<float><<<dim3(HIDDEN / 128, ROWS / 128), dim3(256), 0, stream>>>(
      attn_o, wo_bf, (float*)d_out, ROWS, HIDDEN, QS);
}

// Round 15
// 339.352 us; speedup vs baseline: 1.2242x; 1.1033x over previous
//
#include <hip/hip_runtime.h>
#include <hip/hip_bf16.h>
#include <cstdint>
#include <cstddef>

#define HIDDEN 2048
#define NHEADS 16
#define NKV    8
#define HD     128
#define QS     (NHEADS*HD)      // 2048
#define KVS    (NKV*HD)         // 1024
#define OC     (QS + 2*KVS)     // 4096
#define BB     2
#define SS     2048
#define ROWS   (BB*SS)          // 4096

typedef __bf16 bf16;
typedef __bf16 bf16x8 __attribute__((ext_vector_type(8)));
typedef __bf16 bf16x4 __attribute__((ext_vector_type(4)));
typedef float  f32x4  __attribute__((ext_vector_type(4)));
typedef float  f32x2  __attribute__((ext_vector_type(2)));
typedef int    i32x4  __attribute__((ext_vector_type(4)));

// ---------------- f32 -> bf16 convert (vectorized) ----------------
__global__ __launch_bounds__(256) void k_cvt(const float* __restrict__ src,
                                             bf16* __restrict__ dst, int n8) {
  int i = blockIdx.x * blockDim.x + threadIdx.x;
  int stride = gridDim.x * blockDim.x;
  for (; i < n8; i += stride) {
    const f32x4* s = (const f32x4*)(src + (size_t)i * 8);
    f32x4 a = s[0], b = s[1];
    bf16x8 o;
    o[0]=(bf16)a[0]; o[1]=(bf16)a[1]; o[2]=(bf16)a[2]; o[3]=(bf16)a[3];
    o[4]=(bf16)b[0]; o[5]=(bf16)b[1]; o[6]=(bf16)b[2]; o[7]=(bf16)b[3];
    *(bf16x8*)(dst + (size_t)i * 8) = o;
  }
}

// ---------------- RoPE cos/sin table: tbl[pos][i] = {cos, sin} ----------------
__global__ __launch_bounds__(256) void k_table(float* __restrict__ tbl) {
  int t = blockIdx.x * blockDim.x + threadIdx.x;   // t < SS*64
  int pos = t >> 6, i = t & 63;
  float freq = powf(10000.0f, -(float)i / 64.0f);
  float ang = (float)pos * freq;
  float sv, cv;
  sincosf(ang, &sv, &cv);
  f32x2 v; v[0] = cv; v[1] = sv;
  ((f32x2*)tbl)[t] = v;
}

// ---------------- async global->LDS helper ----------------
__device__ __forceinline__ void gll16(const void* g, void* l) {
  __builtin_amdgcn_global_load_lds((const __attribute__((address_space(1))) void*)g,
                                   (__attribute__((address_space(3))) void*)l, 16, 0, 0);
}

// ---------------- GEMM: C[M][N] = A[M][K] * Bw[N][K]^T  (bf16 in, f32 accum, OT out) ----------------
template <typename OT>
__global__ __launch_bounds__(256) void k_gemm(const bf16* __restrict__ A,
                                              const bf16* __restrict__ Bw,
                                              OT* __restrict__ C,
                                              int M, int N, int K) {
  const int tid = threadIdx.x;
  const int lane = tid & 63;
  const int w = tid >> 6;
  const int m0 = blockIdx.y * 128, n0 = blockIdx.x * 128;
  __shared__ bf16 As[128 * 32];
  __shared__ bf16 Bs[128 * 32];
  f32x4 acc[4][4] = {};
  const int wm = (w >> 1) * 64, wn = (w & 1) * 64;
  const int lr = lane & 15, lg = lane >> 4;
  const int KT = K >> 5;
  for (int kt = 0; kt < KT; ++kt) {
    __syncthreads();
    for (int i = 0; i < 2; ++i) {
      int c = tid + i * 256;
      int row = c >> 2, kc = c & 3;
      gll16(A + (size_t)(m0 + row) * K + kt * 32 + kc * 8, As + (size_t)(c & ~63) * 8);
      gll16(Bw + (size_t)(n0 + row) * K + kt * 32 + kc * 8, Bs + (size_t)(c & ~63) * 8);
    }
    asm volatile("s_waitcnt vmcnt(0)" ::: "memory");
    __syncthreads();
    bf16x8 af[4], bfv[4];
    for (int i = 0; i < 4; ++i)
      af[i] = *(const bf16x8*)(As + (wm + i * 16 + lr) * 32 + lg * 8);
    for (int j = 0; j < 4; ++j)
      bfv[j] = *(const bf16x8*)(Bs + (wn + j * 16 + lr) * 32 + lg * 8);
    for (int i = 0; i < 4; ++i)
      for (int j = 0; j < 4; ++j)
        acc[i][j] = __builtin_amdgcn_mfma_f32_16x16x32_bf16(af[i], bfv[j], acc[i][j], 0, 0, 0);
  }
  for (int i = 0; i < 4; ++i)
    for (int j = 0; j < 4; ++j) {
      int col = n0 + wn + j * 16 + lr;
      for (int r = 0; r < 4; ++r) {
        int row = m0 + wm + i * 16 + lg * 4 + r;
        C[(size_t)row * N + col] = (OT)acc[i][j][r];
      }
    }
}

// ---------------- per-head RMSNorm + RoPE; one wave per (b,s,head24) ----------------
__global__ __launch_bounds__(256) void k_ropenorm(const bf16* __restrict__ qkv,
                                                  bf16* __restrict__ qb, bf16* __restrict__ kb,
                                                  const float* __restrict__ tbl,
                                                  const int* __restrict__ pos,
                                                  const float* __restrict__ qw,
                                                  const float* __restrict__ kw) {
  int gw = blockIdx.x * 4 + (threadIdx.x >> 6);
  int lane = threadIdx.x & 63;
  int h = gw % 24;
  int rem = gw / 24;
  int s = rem & (SS - 1);
  int b = rem >> 11;
  size_t row = (size_t)b * SS + s;
  int col0 = (h < 16) ? h * HD : QS + (h - 16) * HD;
  unsigned u = *(const unsigned*)(qkv + row * OC + col0 + lane * 2);
  float x0 = __uint_as_float((u & 0xffffu) << 16);
  float x1 = __uint_as_float(u & 0xffff0000u);
  float ssq = x0 * x0 + x1 * x1;
  for (int m = 1; m < 64; m <<= 1) ssq += __shfl_xor(ssq, m, 64);
  float r = rsqrtf(ssq * (1.0f / 128.0f) + 1e-6f);
  const float* wv = (h < 16) ? qw : kw;
  float y0 = x0 * r * wv[lane * 2], y1 = x1 * r * wv[lane * 2 + 1];
  float p0 = __shfl_xor(y0, 32, 64), p1 = __shfl_xor(y1, 32, 64);
  int p = pos[row];
  f32x4 cs = *(const f32x4*)(tbl + (size_t)p * 128 + (lane & 31) * 4); // c0,s0,c1,s1
  float o0, o1;
  if (lane < 32) { o0 = y0 * cs[0] - p0 * cs[1]; o1 = y1 * cs[2] - p1 * cs[3]; }
  else           { o0 = y0 * cs[0] + p0 * cs[1]; o1 = y1 * cs[2] + p1 * cs[3]; }
  bf16* dst; size_t drow;
  if (h < 16) { dst = qb; drow = ((size_t)b * NHEADS + h) * SS + s; }
  else        { dst = kb; drow = ((size_t)b * NKV + (h - 16)) * SS + s; }
  bf16 v0 = (bf16)o0, v1 = (bf16)o1;
  unsigned short q0, q1;
  __builtin_memcpy(&q0, &v0, 2); __builtin_memcpy(&q1, &v1, 2);
  *(unsigned*)(dst + drow * HD + lane * 2) = (unsigned)q0 | ((unsigned)q1 << 16);
}

// ---------------- V transpose: qkv v-cols -> vT[b][kv][d][s] ----------------
__global__ __launch_bounds__(256) void k_vt(const bf16* __restrict__ qkv,
                                            bf16* __restrict__ vT) {
  __shared__ bf16 T[64 * 136];       // 64 s-rows x (128 + 8 pad)
  int tid = threadIdx.x;
  int st = blockIdx.x, kv = blockIdx.y, b = blockIdx.z;
  int s0 = st * 64;
  for (int i = 0; i < 4; ++i) {      // 1024 chunks = 64 rows x 16 d-chunks
    int c = tid + i * 256;
    int sl = c >> 4, dc = c & 15;
    i32x4 v = *(const i32x4*)(qkv + (size_t)(b * SS + s0 + sl) * OC + QS + KVS + kv * HD + dc * 8);
    *(i32x4*)(T + sl * 136 + dc * 8) = v;
  }
  __syncthreads();
  for (int i = 0; i < 4; ++i) {
    int c = tid + i * 256;
    int d = c >> 3, sg = c & 7;
    bf16x8 o;
    for (int j = 0; j < 8; ++j) o[j] = T[(sg * 8 + j) * 136 + d];
    *(bf16x8*)(vT + ((size_t)(b * NKV + kv) * HD + d) * SS + s0 + sg * 8) = o;
  }
}

// ---------------- flash attention: R14 + P-LDS bounce + defer-max + setprio ----------------
// 4 waves x 16 q-rows, QBLK=64, gll staging w/ inverse-swizzled source.
// P-regroup via per-wave padded LDS tile (6 LDS ops) instead of 32 ds_bpermute.
__global__ __launch_bounds__(256) void k_attn9(const bf16* __restrict__ qb,
                                               const bf16* __restrict__ kb,
                                               const bf16* __restrict__ vT,
                                               bf16* __restrict__ out) {
  __shared__ bf16 Kl[64 * 128];      // [kv][d], rows XOR-swizzled by (row&7)<<4
  __shared__ bf16 Vl[128 * 64];      // [d][kv], rows XOR-swizzled by (row&7)<<4
  __shared__ bf16 Pl[4][16][88];     // per-wave P[q][kv], stride 88 (2-way banks)
  const int tid = threadIdx.x, lane = tid & 63, w = tid >> 6;
  const int qt = gridDim.x - 1 - blockIdx.x;   // heavy tiles dispatch first
  const int h = blockIdx.y, b = blockIdx.z;
  const int kvh = h >> 1;
  const int lr = lane & 15, lg = lane >> 4;
  const int qbase = qt * 64 + w * 16;
  const float NEG = -3.0e38f;
  bf16x8 qf[4];
  {
    const bf16* qrow = qb + ((size_t)(b * NHEADS + h) * SS + qbase + lr) * HD;
    #pragma unroll
    for (int ks = 0; ks < 4; ++ks) qf[ks] = *(const bf16x8*)(qrow + ks * 32 + lg * 8);
  }
  f32x4 acc[8] = {};                 // acc[nt][r] = O[q=lg*4+r][d=nt*16+lr]
  float m_r = NEG, l_r = 0.0f;
  const bf16* Kg = kb + (size_t)(b * NKV + kvh) * SS * HD;
  const bf16* Vg = vT + (size_t)(b * NKV + kvh) * HD * SS;
  for (int t = 0; t <= qt; ++t) {
    const int kv0 = t * 64;
    __syncthreads();                 // protect previous tile's LDS from overwrite
    // ---- stage K tile via global_load_lds (linear dest, inverse-swizzled source) ----
    #pragma unroll
    for (int i = 0; i < 4; ++i) {
      int c = tid + i * 256;
      int r_ = c >> 4;
      int ch = (c & 15) ^ (r_ & 7);
      gll16(Kg + (size_t)(kv0 + r_) * HD + ch * 8, Kl + (size_t)(c & ~63) * 8);
    }
    // ---- stage V^T tile ----
    #pragma unroll
    for (int i = 0; i < 4; ++i) {
      int c = tid + i * 256;
      int d = c >> 3;
      int ch = (c & 7) ^ (d & 7);
      gll16(Vg + (size_t)d * SS + kv0 + ch * 8, Vl + (size_t)(c & ~63) * 8);
    }
    asm volatile("s_waitcnt vmcnt(0)" ::: "memory");
    __syncthreads();
    // ---- QK^T: S^T[kv][q] via MFMA; K A-fragments from LDS (swizzled read) ----
    f32x4 sf[4];
    __builtin_amdgcn_s_setprio(1);
    #pragma unroll
    for (int mt = 0; mt < 4; ++mt) {
      f32x4 a_ = {0.f, 0.f, 0.f, 0.f};
      const int rrow = mt * 16 + lr;
      #pragma unroll
      for (int ks = 0; ks < 4; ++ks) {
        bf16x8 kf = *(const bf16x8*)((char*)Kl + ((rrow * 256 + ks * 64 + lg * 16) ^ ((rrow & 7) << 4)));
        a_ = __builtin_amdgcn_mfma_f32_16x16x32_bf16(kf, qf[ks], a_, 0, 0, 0);
      }
      sf[mt] = a_;
    }
    __builtin_amdgcn_s_setprio(0);
    // ---- scale + causal mask + row-max (lane holds q=lr, kv=kv0+mt*16+lg*4+r) ----
    const float scl = 0.08838834764831845f;  // 1/sqrt(128)
    const int qg = qbase + lr;
    float pm = NEG;
    #pragma unroll
    for (int mt = 0; mt < 4; ++mt)
      #pragma unroll
      for (int r = 0; r < 4; ++r) {
        int kvg = kv0 + mt * 16 + lg * 4 + r;
        float v = sf[mt][r] * scl;
        if (kvg > qg) v = NEG;
        sf[mt][r] = v;
        pm = fmaxf(pm, v);
      }
    pm = fmaxf(pm, __shfl_xor(pm, 16, 64));
    pm = fmaxf(pm, __shfl_xor(pm, 32, 64));   // pm = row-max for q=lr
    // ---- T13 defer-max: rescale only when the running max grows by > 8 ----
    if (!__all(pm <= m_r + 8.0f)) {
      const float mn = fmaxf(m_r, pm);
      const float scale = __expf(m_r - mn);   // finite-finite, first tile -> 0
      float sr[4];
      #pragma unroll
      for (int r = 0; r < 4; ++r) sr[r] = __shfl(scale, lg * 4 + r, 64);
      #pragma unroll
      for (int nt = 0; nt < 8; ++nt)
        #pragma unroll
        for (int r = 0; r < 4; ++r) acc[nt][r] *= sr[r];
      l_r *= scale;
      m_r = mn;
    }
    // ---- P = exp(S - m_r) (bounded by e^8 under defer); row-sum into l_r ----
    float ts = 0.f;
    #pragma unroll
    for (int mt = 0; mt < 4; ++mt)
      #pragma unroll
      for (int r = 0; r < 4; ++r) {
        float pv = __expf(sf[mt][r] - m_r);    // masked -> 0
        sf[mt][r] = pv;
        ts += pv;
      }
    ts += __shfl_xor(ts, 16, 64);
    ts += __shfl_xor(ts, 32, 64);
    l_r += ts;
    // ---- P -> per-wave padded LDS (replaces 32 ds_bpermute regroup) ----
    // write: row q=lr, cols mt*16+lg*4..+3 ; read: cols kk*32+lg*8..+7
    #pragma unroll
    for (int mt = 0; mt < 4; ++mt) {
      bf16x4 pk;
      #pragma unroll
      for (int r = 0; r < 4; ++r) pk[r] = (bf16)sf[mt][r];
      *(bf16x4*)(&Pl[w][lr][mt * 16 + lg * 4]) = pk;
    }
    // ---- PV: A-fragments from Pl, V B-fragments from Vl ----
    __builtin_amdgcn_s_setprio(1);
    #pragma unroll
    for (int kk = 0; kk < 2; ++kk) {
      bf16x8 pa = *(const bf16x8*)(&Pl[w][lr][kk * 32 + lg * 8]);
      #pragma unroll
      for (int nt = 0; nt < 8; ++nt) {
        const int d = nt * 16 + lr;
        bf16x8 vbf = *(const bf16x8*)((char*)Vl + ((d * 128 + kk * 64 + lg * 16) ^ ((d & 7) << 4)));
        acc[nt] = __builtin_amdgcn_mfma_f32_16x16x32_bf16(pa, vbf, acc[nt], 0, 0, 0);
      }
    }
    __builtin_amdgcn_s_setprio(0);
  }
  // ---- epilogue: normalize rows and store ----
  const float inv = 1.0f / l_r;     // lane holds inv for q=lr
  float ir[4];
  #pragma unroll
  for (int r = 0; r < 4; ++r) ir[r] = __shfl(inv, lg * 4 + r, 64);
  #pragma unroll
  for (int nt = 0; nt < 8; ++nt)
    #pragma unroll
    for (int r = 0; r < 4; ++r) {
      size_t row = (size_t)b * SS + qbase + lg * 4 + r;
      out[row * QS + h * HD + nt * 16 + lr] = (bf16)(acc[nt][r] * ir[r]);
    }
}

// ---------------- launcher ----------------
extern "C" void kernel_launch(void* const* d_in, const int* in_sizes, int n_in,
                              void* d_out, int out_size, void* d_ws, size_t ws_size,
                              hipStream_t stream) {
  const int*   pos  = (const int*)d_in[0];
  const float* hid  = (const float*)d_in[1];
  const float* wqkv = (const float*)d_in[2];
  const float* wo   = (const float*)d_in[3];
  const float* qw   = (const float*)d_in[4];
  const float* kw   = (const float*)d_in[5];
  char* ws = (char*)d_ws;
  bf16* hid_bf  = (bf16*)(ws + 0);          // 16MB, reused as attn_out
  bf16* attn_o  = hid_bf;
  bf16* wqkv_bf = (bf16*)(ws + 16777216);   // 16MB, reused as q_buf
  bf16* q_buf   = wqkv_bf;
  bf16* k_buf   = (bf16*)(ws + 33554432);   // 8MB, reused as wo_bf
  bf16* wo_bf   = k_buf;
  bf16* qkv     = (bf16*)(ws + 41943040);   // 32MB
  bf16* vT      = (bf16*)(ws + 75497472);   // 8MB
  float* tbl    = (float*)(ws + 83886080);  // 1MB

  k_cvt<<<dim3(2048), dim3(256), 0, stream>>>(hid,  hid_bf,  ROWS * HIDDEN / 8);
  k_cvt<<<dim3(2048), dim3(256), 0, stream>>>(wqkv, wqkv_bf, OC * HIDDEN / 8);
  k_table<<<dim3(512), dim3(256), 0, stream>>>(tbl);
  k_gemm<bf16><<<dim3(OC / 128, ROWS / 128), dim3(256), 0, stream>>>(
      hid_bf, wqkv_bf, qkv, ROWS, OC, HIDDEN);
  k_ropenorm<<<dim3(ROWS * 24 / 4), dim3(256), 0, stream>>>(
      qkv, q_buf, k_buf, tbl, pos, qw, kw);
  k_vt<<<dim3(SS / 64, NKV, BB), dim3(256), 0, stream>>>(qkv, vT);
  k_attn9<<<dim3(SS / 64, NHEADS, BB), dim3(256), 0, stream>>>(
      q_buf, k_buf, vT, attn_o);
  k_cvt<<<dim3(2048), dim3(256), 0, stream>>>(wo, wo_bf, HIDDEN * QS / 8);
  k_gemm<float><<<dim3(HIDDEN / 128, ROWS / 128), dim3(256), 0, stream>>>(
      attn_o, wo_bf, (float*)d_out, ROWS, HIDDEN, QS);
}

// Round 16
// 302.841 us; speedup vs baseline: 1.3718x; 1.1206x over previous
//
#include <hip/hip_runtime.h>
#include <hip/hip_bf16.h>
#include <cstdint>
#include <cstddef>

#define HIDDEN 2048
#define NHEADS 16
#define NKV    8
#define HD     128
#define QS     (NHEADS*HD)      // 2048
#define KVS    (NKV*HD)         // 1024
#define OC     (QS + 2*KVS)     // 4096
#define BB     2
#define SS     2048
#define ROWS   (BB*SS)          // 4096

typedef __bf16 bf16;
typedef __bf16 bf16x8 __attribute__((ext_vector_type(8)));
typedef __bf16 bf16x4 __attribute__((ext_vector_type(4)));
typedef float  f32x4  __attribute__((ext_vector_type(4)));
typedef float  f32x2  __attribute__((ext_vector_type(2)));
typedef int    i32x4  __attribute__((ext_vector_type(4)));

// ---------------- f32 -> bf16 convert (vectorized) ----------------
__global__ __launch_bounds__(256) void k_cvt(const float* __restrict__ src,
                                             bf16* __restrict__ dst, int n8) {
  int i = blockIdx.x * blockDim.x + threadIdx.x;
  int stride = gridDim.x * blockDim.x;
  for (; i < n8; i += stride) {
    const f32x4* s = (const f32x4*)(src + (size_t)i * 8);
    f32x4 a = s[0], b = s[1];
    bf16x8 o;
    o[0]=(bf16)a[0]; o[1]=(bf16)a[1]; o[2]=(bf16)a[2]; o[3]=(bf16)a[3];
    o[4]=(bf16)b[0]; o[5]=(bf16)b[1]; o[6]=(bf16)b[2]; o[7]=(bf16)b[3];
    *(bf16x8*)(dst + (size_t)i * 8) = o;
  }
}

// ---------------- RoPE cos/sin table: tbl[pos][i] = {cos, sin} ----------------
__global__ __launch_bounds__(256) void k_table(float* __restrict__ tbl) {
  int t = blockIdx.x * blockDim.x + threadIdx.x;   // t < SS*64
  int pos = t >> 6, i = t & 63;
  float freq = powf(10000.0f, -(float)i / 64.0f);
  float ang = (float)pos * freq;
  float sv, cv;
  sincosf(ang, &sv, &cv);
  f32x2 v; v[0] = cv; v[1] = sv;
  ((f32x2*)tbl)[t] = v;
}

// ---------------- async global->LDS helper ----------------
__device__ __forceinline__ void gll16(const void* g, void* l) {
  __builtin_amdgcn_global_load_lds((const __attribute__((address_space(1))) void*)g,
                                   (__attribute__((address_space(3))) void*)l, 16, 0, 0);
}

// ---------------- GEMM: C[M][N] = A[M][K] * Bw[N][K]^T  (bf16 in, f32 accum, OT out) ----------------
// BK=64 (half the barriers vs BK=32) with XOR-swizzled LDS tiles:
// linear gll dest + inverse-swizzled source chunk ch = kc ^ (row&7); reads XOR the
// same (lr&7)<<4 -> conflict-free ds_read_b128. K must be a multiple of 64.
template <typename OT>
__global__ __launch_bounds__(256) void k_gemm(const bf16* __restrict__ A,
                                              const bf16* __restrict__ Bw,
                                              OT* __restrict__ C,
                                              int M, int N, int K) {
  const int tid = threadIdx.x;
  const int lane = tid & 63;
  const int w = tid >> 6;
  const int m0 = blockIdx.y * 128, n0 = blockIdx.x * 128;
  __shared__ bf16 As[128 * 64];
  __shared__ bf16 Bs[128 * 64];
  f32x4 acc[4][4] = {};
  const int wm = (w >> 1) * 64, wn = (w & 1) * 64;
  const int lr = lane & 15, lg = lane >> 4;
  const int KT = K >> 6;
  for (int kt = 0; kt < KT; ++kt) {
    __syncthreads();
    #pragma unroll
    for (int i = 0; i < 4; ++i) {
      int c = tid + i * 256;              // 1024 chunks of 16B per matrix
      int row = c >> 3, kc = c & 7;
      int ch = kc ^ (row & 7);            // inverse swizzle on the SOURCE
      gll16(A + (size_t)(m0 + row) * K + kt * 64 + ch * 8, As + (size_t)(c & ~63) * 8);
      gll16(Bw + (size_t)(n0 + row) * K + kt * 64 + ch * 8, Bs + (size_t)(c & ~63) * 8);
    }
    asm volatile("s_waitcnt vmcnt(0)" ::: "memory");
    __syncthreads();
    #pragma unroll
    for (int kh = 0; kh < 2; ++kh) {
      bf16x8 af[4], bfv[4];
      #pragma unroll
      for (int i = 0; i < 4; ++i) {
        int row = wm + i * 16 + lr;       // row&7 == lr&7
        af[i] = *(const bf16x8*)((char*)As + ((row * 128 + kh * 64 + lg * 16) ^ ((lr & 7) << 4)));
      }
      #pragma unroll
      for (int j = 0; j < 4; ++j) {
        int row = wn + j * 16 + lr;
        bfv[j] = *(const bf16x8*)((char*)Bs + ((row * 128 + kh * 64 + lg * 16) ^ ((lr & 7) << 4)));
      }
      #pragma unroll
      for (int i = 0; i < 4; ++i)
        #pragma unroll
        for (int j = 0; j < 4; ++j)
          acc[i][j] = __builtin_amdgcn_mfma_f32_16x16x32_bf16(af[i], bfv[j], acc[i][j], 0, 0, 0);
    }
  }
  for (int i = 0; i < 4; ++i)
    for (int j = 0; j < 4; ++j) {
      int col = n0 + wn + j * 16 + lr;
      for (int r = 0; r < 4; ++r) {
        int row = m0 + wm + i * 16 + lg * 4 + r;
        C[(size_t)row * N + col] = (OT)acc[i][j][r];
      }
    }
}

// ---------------- per-head RMSNorm + RoPE; one wave per (b,s,head24) ----------------
__global__ __launch_bounds__(256) void k_ropenorm(const bf16* __restrict__ qkv,
                                                  bf16* __restrict__ qb, bf16* __restrict__ kb,
                                                  const float* __restrict__ tbl,
                                                  const int* __restrict__ pos,
                                                  const float* __restrict__ qw,
                                                  const float* __restrict__ kw) {
  int gw = blockIdx.x * 4 + (threadIdx.x >> 6);
  int lane = threadIdx.x & 63;
  int h = gw % 24;
  int rem = gw / 24;
  int s = rem & (SS - 1);
  int b = rem >> 11;
  size_t row = (size_t)b * SS + s;
  int col0 = (h < 16) ? h * HD : QS + (h - 16) * HD;
  unsigned u = *(const unsigned*)(qkv + row * OC + col0 + lane * 2);
  float x0 = __uint_as_float((u & 0xffffu) << 16);
  float x1 = __uint_as_float(u & 0xffff0000u);
  float ssq = x0 * x0 + x1 * x1;
  for (int m = 1; m < 64; m <<= 1) ssq += __shfl_xor(ssq, m, 64);
  float r = rsqrtf(ssq * (1.0f / 128.0f) + 1e-6f);
  const float* wv = (h < 16) ? qw : kw;
  float y0 = x0 * r * wv[lane * 2], y1 = x1 * r * wv[lane * 2 + 1];
  float p0 = __shfl_xor(y0, 32, 64), p1 = __shfl_xor(y1, 32, 64);
  int p = pos[row];
  f32x4 cs = *(const f32x4*)(tbl + (size_t)p * 128 + (lane & 31) * 4); // c0,s0,c1,s1
  float o0, o1;
  if (lane < 32) { o0 = y0 * cs[0] - p0 * cs[1]; o1 = y1 * cs[2] - p1 * cs[3]; }
  else           { o0 = y0 * cs[0] + p0 * cs[1]; o1 = y1 * cs[2] + p1 * cs[3]; }
  bf16* dst; size_t drow;
  if (h < 16) { dst = qb; drow = ((size_t)b * NHEADS + h) * SS + s; }
  else        { dst = kb; drow = ((size_t)b * NKV + (h - 16)) * SS + s; }
  bf16 v0 = (bf16)o0, v1 = (bf16)o1;
  unsigned short q0, q1;
  __builtin_memcpy(&q0, &v0, 2); __builtin_memcpy(&q1, &v1, 2);
  *(unsigned*)(dst + drow * HD + lane * 2) = (unsigned)q0 | ((unsigned)q1 << 16);
}

// ---------------- V transpose: qkv v-cols -> vT[b][kv][d][s] ----------------
__global__ __launch_bounds__(256) void k_vt(const bf16* __restrict__ qkv,
                                            bf16* __restrict__ vT) {
  __shared__ bf16 T[64 * 136];       // 64 s-rows x (128 + 8 pad)
  int tid = threadIdx.x;
  int st = blockIdx.x, kv = blockIdx.y, b = blockIdx.z;
  int s0 = st * 64;
  for (int i = 0; i < 4; ++i) {      // 1024 chunks = 64 rows x 16 d-chunks
    int c = tid + i * 256;
    int sl = c >> 4, dc = c & 15;
    i32x4 v = *(const i32x4*)(qkv + (size_t)(b * SS + s0 + sl) * OC + QS + KVS + kv * HD + dc * 8);
    *(i32x4*)(T + sl * 136 + dc * 8) = v;
  }
  __syncthreads();
  for (int i = 0; i < 4; ++i) {
    int c = tid + i * 256;
    int d = c >> 3, sg = c & 7;
    bf16x8 o;
    for (int j = 0; j < 8; ++j) o[j] = T[(sg * 8 + j) * 136 + d];
    *(bf16x8*)(vT + ((size_t)(b * NKV + kv) * HD + d) * SS + s0 + sg * 8) = o;
  }
}

// ---------------- flash attention: R15 + Pl swizzled to 40KB (4 blocks/CU) ----------------
// 4 waves x 16 q-rows, QBLK=64, gll staging w/ inverse-swizzled source, P-LDS bounce,
// defer-max (T13), setprio (T5). LDS = 16K + 16K + 8K = 40960 B exactly.
__global__ __launch_bounds__(256) void k_attn9(const bf16* __restrict__ qb,
                                               const bf16* __restrict__ kb,
                                               const bf16* __restrict__ vT,
                                               bf16* __restrict__ out) {
  __shared__ bf16 Kl[64 * 128];      // [kv][d], rows XOR-swizzled by (row&7)<<4
  __shared__ bf16 Vl[128 * 64];      // [d][kv], rows XOR-swizzled by (row&7)<<4
  __shared__ bf16 Pl[4][16 * 64];    // per-wave P[q][kv], row-XOR swizzled (128B rows)
  const int tid = threadIdx.x, lane = tid & 63, w = tid >> 6;
  const int qt = gridDim.x - 1 - blockIdx.x;   // heavy tiles dispatch first
  const int h = blockIdx.y, b = blockIdx.z;
  const int kvh = h >> 1;
  const int lr = lane & 15, lg = lane >> 4;
  const int qbase = qt * 64 + w * 16;
  const float NEG = -3.0e38f;
  bf16x8 qf[4];
  {
    const bf16* qrow = qb + ((size_t)(b * NHEADS + h) * SS + qbase + lr) * HD;
    #pragma unroll
    for (int ks = 0; ks < 4; ++ks) qf[ks] = *(const bf16x8*)(qrow + ks * 32 + lg * 8);
  }
  f32x4 acc[8] = {};                 // acc[nt][r] = O[q=lg*4+r][d=nt*16+lr]
  float m_r = NEG, l_r = 0.0f;
  const bf16* Kg = kb + (size_t)(b * NKV + kvh) * SS * HD;
  const bf16* Vg = vT + (size_t)(b * NKV + kvh) * HD * SS;
  for (int t = 0; t <= qt; ++t) {
    const int kv0 = t * 64;
    __syncthreads();                 // protect previous tile's LDS from overwrite
    // ---- stage K tile via global_load_lds (linear dest, inverse-swizzled source) ----
    #pragma unroll
    for (int i = 0; i < 4; ++i) {
      int c = tid + i * 256;
      int r_ = c >> 4;
      int ch = (c & 15) ^ (r_ & 7);
      gll16(Kg + (size_t)(kv0 + r_) * HD + ch * 8, Kl + (size_t)(c & ~63) * 8);
    }
    // ---- stage V^T tile ----
    #pragma unroll
    for (int i = 0; i < 4; ++i) {
      int c = tid + i * 256;
      int d = c >> 3;
      int ch = (c & 7) ^ (d & 7);
      gll16(Vg + (size_t)d * SS + kv0 + ch * 8, Vl + (size_t)(c & ~63) * 8);
    }
    asm volatile("s_waitcnt vmcnt(0)" ::: "memory");
    __syncthreads();
    // ---- QK^T: S^T[kv][q] via MFMA; K A-fragments from LDS (swizzled read) ----
    f32x4 sf[4];
    __builtin_amdgcn_s_setprio(1);
    #pragma unroll
    for (int mt = 0; mt < 4; ++mt) {
      f32x4 a_ = {0.f, 0.f, 0.f, 0.f};
      const int rrow = mt * 16 + lr;
      #pragma unroll
      for (int ks = 0; ks < 4; ++ks) {
        bf16x8 kf = *(const bf16x8*)((char*)Kl + ((rrow * 256 + ks * 64 + lg * 16) ^ ((rrow & 7) << 4)));
        a_ = __builtin_amdgcn_mfma_f32_16x16x32_bf16(kf, qf[ks], a_, 0, 0, 0);
      }
      sf[mt] = a_;
    }
    __builtin_amdgcn_s_setprio(0);
    // ---- scale + causal mask + row-max (lane holds q=lr, kv=kv0+mt*16+lg*4+r) ----
    const float scl = 0.08838834764831845f;  // 1/sqrt(128)
    const int qg = qbase + lr;
    float pm = NEG;
    #pragma unroll
    for (int mt = 0; mt < 4; ++mt)
      #pragma unroll
      for (int r = 0; r < 4; ++r) {
        int kvg = kv0 + mt * 16 + lg * 4 + r;
        float v = sf[mt][r] * scl;
        if (kvg > qg) v = NEG;
        sf[mt][r] = v;
        pm = fmaxf(pm, v);
      }
    pm = fmaxf(pm, __shfl_xor(pm, 16, 64));
    pm = fmaxf(pm, __shfl_xor(pm, 32, 64));   // pm = row-max for q=lr
    // ---- T13 defer-max: rescale only when the running max grows by > 8 ----
    if (!__all(pm <= m_r + 8.0f)) {
      const float mn = fmaxf(m_r, pm);
      const float scale = __expf(m_r - mn);   // finite-finite, first tile -> 0
      float sr[4];
      #pragma unroll
      for (int r = 0; r < 4; ++r) sr[r] = __shfl(scale, lg * 4 + r, 64);
      #pragma unroll
      for (int nt = 0; nt < 8; ++nt)
        #pragma unroll
        for (int r = 0; r < 4; ++r) acc[nt][r] *= sr[r];
      l_r *= scale;
      m_r = mn;
    }
    // ---- P = exp(S - m_r) (bounded by e^8 under defer); row-sum into l_r ----
    float ts = 0.f;
    #pragma unroll
    for (int mt = 0; mt < 4; ++mt)
      #pragma unroll
      for (int r = 0; r < 4; ++r) {
        float pv = __expf(sf[mt][r] - m_r);    // masked -> 0
        sf[mt][r] = pv;
        ts += pv;
      }
    ts += __shfl_xor(ts, 16, 64);
    ts += __shfl_xor(ts, 32, 64);
    l_r += ts;
    // ---- P -> per-wave swizzled LDS (write 8B, read 16B; both XOR (lr&7)<<4) ----
    #pragma unroll
    for (int mt = 0; mt < 4; ++mt) {
      bf16x4 pk;
      #pragma unroll
      for (int r = 0; r < 4; ++r) pk[r] = (bf16)sf[mt][r];
      *(bf16x4*)((char*)&Pl[w][0] + ((lr * 128 + mt * 32 + lg * 8) ^ ((lr & 7) << 4))) = pk;
    }
    // ---- PV: A-fragments from Pl, V B-fragments from Vl ----
    __builtin_amdgcn_s_setprio(1);
    #pragma unroll
    for (int kk = 0; kk < 2; ++kk) {
      bf16x8 pa = *(const bf16x8*)((char*)&Pl[w][0] + ((lr * 128 + kk * 64 + lg * 16) ^ ((lr & 7) << 4)));
      #pragma unroll
      for (int nt = 0; nt < 8; ++nt) {
        const int d = nt * 16 + lr;
        bf16x8 vbf = *(const bf16x8*)((char*)Vl + ((d * 128 + kk * 64 + lg * 16) ^ ((d & 7) << 4)));
        acc[nt] = __builtin_amdgcn_mfma_f32_16x16x32_bf16(pa, vbf, acc[nt], 0, 0, 0);
      }
    }
    __builtin_amdgcn_s_setprio(0);
  }
  // ---- epilogue: normalize rows and store ----
  const float inv = 1.0f / l_r;     // lane holds inv for q=lr
  float ir[4];
  #pragma unroll
  for (int r = 0; r < 4; ++r) ir[r] = __shfl(inv, lg * 4 + r, 64);
  #pragma unroll
  for (int nt = 0; nt < 8; ++nt)
    #pragma unroll
    for (int r = 0; r < 4; ++r) {
      size_t row = (size_t)b * SS + qbase + lg * 4 + r;
      out[row * QS + h * HD + nt * 16 + lr] = (bf16)(acc[nt][r] * ir[r]);
    }
}

// ---------------- launcher ----------------
extern "C" void kernel_launch(void* const* d_in, const int* in_sizes, int n_in,
                              void* d_out, int out_size, void* d_ws, size_t ws_size,
                              hipStream_t stream) {
  const int*   pos  = (const int*)d_in[0];
  const float* hid  = (const float*)d_in[1];
  const float* wqkv = (const float*)d_in[2];
  const float* wo   = (const float*)d_in[3];
  const float* qw   = (const float*)d_in[4];
  const float* kw   = (const float*)d_in[5];
  char* ws = (char*)d_ws;
  bf16* hid_bf  = (bf16*)(ws + 0);          // 16MB, reused as attn_out
  bf16* attn_o  = hid_bf;
  bf16* wqkv_bf = (bf16*)(ws + 16777216);   // 16MB, reused as q_buf
  bf16* q_buf   = wqkv_bf;
  bf16* k_buf   = (bf16*)(ws + 33554432);   // 8MB, reused as wo_bf
  bf16* wo_bf   = k_buf;
  bf16* qkv     = (bf16*)(ws + 41943040);   // 32MB
  bf16* vT      = (bf16*)(ws + 75497472);   // 8MB
  float* tbl    = (float*)(ws + 83886080);  // 1MB

  k_cvt<<<dim3(2048), dim3(256), 0, stream>>>(hid,  hid_bf,  ROWS * HIDDEN / 8);
  k_cvt<<<dim3(2048), dim3(256), 0, stream>>>(wqkv, wqkv_bf, OC * HIDDEN / 8);
  k_table<<<dim3(512), dim3(256), 0, stream>>>(tbl);
  k_gemm<bf16><<<dim3(OC / 128, ROWS / 128), dim3(256), 0, stream>>>(
      hid_bf, wqkv_bf, qkv, ROWS, OC, HIDDEN);
  k_ropenorm<<<dim3(ROWS * 24 / 4), dim3(256), 0, stream>>>(
      qkv, q_buf, k_buf, tbl, pos, qw, kw);
  k_vt<<<dim3(SS / 64, NKV, BB), dim3(256), 0, stream>>>(qkv, vT);
  k_attn9<<<dim3(SS / 64, NHEADS, BB), dim3(256), 0, stream>>>(
      q_buf, k_buf, vT, attn_o);
  k_cvt<<<dim3(2048), dim3(256), 0, stream>>>(wo, wo_bf, HIDDEN * QS / 8);
  k_gemm<float><<<dim3(HIDDEN / 128, ROWS / 128), dim3(256), 0, stream>>>(
      attn_o, wo_bf, (float*)d_out, ROWS, HIDDEN, QS);
}